// Round 5
// baseline (358.334 us; speedup 1.0000x reference)
//
#include <hip/hip_runtime.h>
#include <hip/hip_bf16.h>
#include <math.h>

constexpr int C = 1000;
constexpr int B = 65536;
constexpr int SP = 1024;         // padded bf16 S row stride (2 KB/row, 16B-aligned)
constexpr float SMOOTH = 0.1f;
constexpr int NBLK2 = B / 8;     // 4 waves per block, 2 samples per wave

typedef float f4 __attribute__((ext_vector_type(4)));
typedef short s8 __attribute__((ext_vector_type(8)));

__device__ inline float bf2f(short u) {
    unsigned v = ((unsigned)(unsigned short)u) << 16;
    return __builtin_bit_cast(float, v);
}

__device__ inline float wave_reduce_max(float v) {
    #pragma unroll
    for (int off = 32; off > 0; off >>= 1)
        v = fmaxf(v, __shfl_xor(v, off, 64));
    return v;
}
__device__ inline float wave_reduce_sum(float v) {
    #pragma unroll
    for (int off = 32; off > 0; off >>= 1)
        v += __shfl_xor(v, off, 64);
    return v;
}
__device__ inline float block_reduce_max(float v, float* sm) {
    v = wave_reduce_max(v);
    int wave = threadIdx.x >> 6, lane = threadIdx.x & 63;
    if (lane == 0) sm[wave] = v;
    __syncthreads();
    float r = fmaxf(fmaxf(sm[0], sm[1]), fmaxf(sm[2], sm[3]));
    __syncthreads();
    return r;
}
__device__ inline float block_reduce_sum(float v, float* sm) {
    v = wave_reduce_sum(v);
    int wave = threadIdx.x >> 6, lane = threadIdx.x & 63;
    if (lane == 0) sm[wave] = v;
    __syncthreads();
    float r = sm[0] + sm[1] + sm[2] + sm[3];
    __syncthreads();
    return r;
}

// Kernel 1: per class row t: A = softmax(row); S[t,j] = 0.1*(1-A_j)/(sumA-A_tt),
// S[t,t] = 0.9, stored bf16 with row stride SP (cols C..SP-1 zeroed);
// Srow[t] = sum_j S[t,j] in f32.
__global__ __launch_bounds__(256) void smooth_kernel(
        const float* __restrict__ ca, __hip_bfloat16* __restrict__ S,
        float* __restrict__ Srow) {
    __shared__ float sm[4];
    __shared__ float diag_sh;
    int t = blockIdx.x;
    int tid = threadIdx.x;
    const float* row = ca + (size_t)t * C;

    float v[4];
    float m = -INFINITY;
    #pragma unroll
    for (int k = 0; k < 4; k++) {
        int j = tid + k * 256;
        v[k] = (j < C) ? row[j] : -INFINITY;
        m = fmaxf(m, v[k]);
    }
    m = block_reduce_max(m, sm);

    float a[4];
    float zl = 0.f;
    #pragma unroll
    for (int k = 0; k < 4; k++) {
        int j = tid + k * 256;
        a[k] = (j < C) ? __expf(v[k] - m) : 0.f;
        zl += a[k];
    }
    float z = block_reduce_sum(zl, sm);
    float inv_z = 1.0f / z;

    float sumA_l = 0.f;
    #pragma unroll
    for (int k = 0; k < 4; k++) {
        a[k] *= inv_z;
        sumA_l += a[k];
        int j = tid + k * 256;
        if (j == t) diag_sh = a[k];   // visible after syncthreads inside next reduce
    }
    float sumA = block_reduce_sum(sumA_l, sm);

    float sums = sumA - diag_sh;
    float coef = SMOOTH / sums;
    __hip_bfloat16* Srt = S + (size_t)t * SP;
    float srow_l = 0.f;
    #pragma unroll
    for (int k = 0; k < 4; k++) {
        int j = tid + k * 256;      // covers 0..1023 exactly
        float s = 0.f;
        if (j < C) {
            s = (j == t) ? (1.0f - SMOOTH) : (1.0f - a[k]) * coef;
            srow_l += s;
        }
        Srt[j] = __float2bfloat16(s);   // pad cols get 0
    }
    float srow = block_reduce_sum(srow_l, sm);
    if (tid == 0) Srow[t] = srow;
}

// Kernel 2: TWO samples per wave (2x memory-level parallelism), plain loads
// (no non-temporal hint). Unshifted logsumexp is safe (x ~ N(0,1)).
// loss_b = log(sum_j exp(x_bj)) * Srow[t_b] - dot(S[t_b,:], x[b,:])
__global__ __launch_bounds__(256) void loss_kernel(
        const float* __restrict__ x, const short* __restrict__ S,
        const float* __restrict__ Srow, const int* __restrict__ tgt,
        float* __restrict__ partials) {
    int wave = threadIdx.x >> 6, lane = threadIdx.x & 63;
    int b0 = (blockIdx.x * 4 + wave) * 2;   // samples b0, b0+1
    int b1 = b0 + 1;

    int t0 = tgt[b0];
    int t1 = tgt[b1];
    const f4* xr0 = (const f4*)(x + (size_t)b0 * C);
    const f4* xr1 = (const f4*)(x + (size_t)b1 * C);
    const s8* sr0 = (const s8*)(S + (size_t)t0 * SP);
    const s8* sr1 = (const s8*)(S + (size_t)t1 * SP);

    int c0 = lane, c1 = lane + 64;
    bool ok = (c1 <= 124);                  // chunk 124 = cols 992..999 (last valid)

    // issue all 12 loads up front
    f4 xa0 = xr0[2 * c0],     xb0 = xr0[2 * c0 + 1];
    f4 xa1 = xr1[2 * c0],     xb1 = xr1[2 * c0 + 1];
    f4 xc0 = {0.f, 0.f, 0.f, 0.f}, xd0 = {0.f, 0.f, 0.f, 0.f};
    f4 xc1 = {0.f, 0.f, 0.f, 0.f}, xd1 = {0.f, 0.f, 0.f, 0.f};
    if (ok) {
        xc0 = xr0[2 * c1]; xd0 = xr0[2 * c1 + 1];
        xc1 = xr1[2 * c1]; xd1 = xr1[2 * c1 + 1];
    }
    s8 sv00 = sr0[c0], sv01 = sr0[c1];      // pad chunks are zeros, in-bounds
    s8 sv10 = sr1[c0], sv11 = sr1[c1];
    float ss0 = Srow[t0];
    float ss1 = Srow[t1];

    float z0 = 0.f, d0 = 0.f, z1 = 0.f, d1 = 0.f;

    z0 += (__expf(xa0.x) + __expf(xa0.y)) + (__expf(xa0.z) + __expf(xa0.w));
    z0 += (__expf(xb0.x) + __expf(xb0.y)) + (__expf(xb0.z) + __expf(xb0.w));
    z0 += (__expf(xc0.x) + __expf(xc0.y)) + (__expf(xc0.z) + __expf(xc0.w));
    z0 += (__expf(xd0.x) + __expf(xd0.y)) + (__expf(xd0.z) + __expf(xd0.w));
    z1 += (__expf(xa1.x) + __expf(xa1.y)) + (__expf(xa1.z) + __expf(xa1.w));
    z1 += (__expf(xb1.x) + __expf(xb1.y)) + (__expf(xb1.z) + __expf(xb1.w));
    z1 += (__expf(xc1.x) + __expf(xc1.y)) + (__expf(xc1.z) + __expf(xc1.w));
    z1 += (__expf(xd1.x) + __expf(xd1.y)) + (__expf(xd1.z) + __expf(xd1.w));
    if (!ok) { z0 -= 8.0f; z1 -= 8.0f; }    // remove exp(0)=1 pad terms

    d0 = fmaf(bf2f(sv00[0]), xa0.x, d0);
    d0 = fmaf(bf2f(sv00[1]), xa0.y, d0);
    d0 = fmaf(bf2f(sv00[2]), xa0.z, d0);
    d0 = fmaf(bf2f(sv00[3]), xa0.w, d0);
    d0 = fmaf(bf2f(sv00[4]), xb0.x, d0);
    d0 = fmaf(bf2f(sv00[5]), xb0.y, d0);
    d0 = fmaf(bf2f(sv00[6]), xb0.z, d0);
    d0 = fmaf(bf2f(sv00[7]), xb0.w, d0);
    d0 = fmaf(bf2f(sv01[0]), xc0.x, d0);
    d0 = fmaf(bf2f(sv01[1]), xc0.y, d0);
    d0 = fmaf(bf2f(sv01[2]), xc0.z, d0);
    d0 = fmaf(bf2f(sv01[3]), xc0.w, d0);
    d0 = fmaf(bf2f(sv01[4]), xd0.x, d0);
    d0 = fmaf(bf2f(sv01[5]), xd0.y, d0);
    d0 = fmaf(bf2f(sv01[6]), xd0.z, d0);
    d0 = fmaf(bf2f(sv01[7]), xd0.w, d0);

    d1 = fmaf(bf2f(sv10[0]), xa1.x, d1);
    d1 = fmaf(bf2f(sv10[1]), xa1.y, d1);
    d1 = fmaf(bf2f(sv10[2]), xa1.z, d1);
    d1 = fmaf(bf2f(sv10[3]), xa1.w, d1);
    d1 = fmaf(bf2f(sv10[4]), xb1.x, d1);
    d1 = fmaf(bf2f(sv10[5]), xb1.y, d1);
    d1 = fmaf(bf2f(sv10[6]), xb1.z, d1);
    d1 = fmaf(bf2f(sv10[7]), xb1.w, d1);
    d1 = fmaf(bf2f(sv11[0]), xc1.x, d1);
    d1 = fmaf(bf2f(sv11[1]), xc1.y, d1);
    d1 = fmaf(bf2f(sv11[2]), xc1.z, d1);
    d1 = fmaf(bf2f(sv11[3]), xc1.w, d1);
    d1 = fmaf(bf2f(sv11[4]), xd1.x, d1);
    d1 = fmaf(bf2f(sv11[5]), xd1.y, d1);
    d1 = fmaf(bf2f(sv11[6]), xd1.z, d1);
    d1 = fmaf(bf2f(sv11[7]), xd1.w, d1);

    // fused quad reduction: one 6-round shfl pass for (z0,d0,z1,d1)
    #pragma unroll
    for (int off = 32; off > 0; off >>= 1) {
        z0 += __shfl_xor(z0, off, 64);
        d0 += __shfl_xor(d0, off, 64);
        z1 += __shfl_xor(z1, off, 64);
        d1 += __shfl_xor(d1, off, 64);
    }

    if (lane == 0) {
        partials[b0] = __logf(z0) * ss0 - d0;
        partials[b1] = __logf(z1) * ss1 - d1;
    }
}

// Kernel 3: sum B partials -> out = sum / B. Single 1024-thread block.
__global__ __launch_bounds__(1024) void reduce_kernel(
        const float* __restrict__ partials, float* __restrict__ out) {
    __shared__ float sm[16];
    const f4* p4 = (const f4*)partials;      // B/4 = 16384 f4 = 1024 threads * 16
    float s = 0.f;
    #pragma unroll
    for (int k = 0; k < 16; k++) {
        f4 v = p4[threadIdx.x + k * 1024];
        s += (v.x + v.y) + (v.z + v.w);
    }
    s = wave_reduce_sum(s);
    int wave = threadIdx.x >> 6, lane = threadIdx.x & 63;
    if (lane == 0) sm[wave] = s;
    __syncthreads();
    if (threadIdx.x == 0) {
        float tot = 0.f;
        #pragma unroll
        for (int w = 0; w < 16; w++) tot += sm[w];
        out[0] = tot * (1.0f / (float)B);
    }
}

extern "C" void kernel_launch(void* const* d_in, const int* in_sizes, int n_in,
                              void* d_out, int out_size, void* d_ws, size_t ws_size,
                              hipStream_t stream) {
    const float* x   = (const float*)d_in[0];
    const float* ca  = (const float*)d_in[1];
    const int*   tgt = (const int*)d_in[2];
    float* out = (float*)d_out;

    __hip_bfloat16* S = (__hip_bfloat16*)d_ws;        // C*SP bf16 = 2 MB
    float* Srow       = (float*)(S + (size_t)C * SP); // C floats
    float* partials   = Srow + C;                     // B floats = 256 KB

    smooth_kernel<<<C, 256, 0, stream>>>(ca, S, Srow);
    loss_kernel<<<NBLK2, 256, 0, stream>>>(x, (const short*)S, Srow, tgt, partials);
    reduce_kernel<<<1, 1024, 0, stream>>>(partials, out);
}

// Round 6
// 342.760 us; speedup vs baseline: 1.0454x; 1.0454x over previous
//
#include <hip/hip_runtime.h>
#include <hip/hip_bf16.h>
#include <math.h>

constexpr int C = 1000;
constexpr int B = 65536;
constexpr float SMOOTH = 0.1f;
constexpr int NBLK = B / 4;   // 4 waves per block, 1 sample per wave

typedef float f4 __attribute__((ext_vector_type(4)));

__device__ inline float wave_reduce_max(float v) {
    #pragma unroll
    for (int off = 32; off > 0; off >>= 1)
        v = fmaxf(v, __shfl_xor(v, off, 64));
    return v;
}
__device__ inline float wave_reduce_sum(float v) {
    #pragma unroll
    for (int off = 32; off > 0; off >>= 1)
        v += __shfl_xor(v, off, 64);
    return v;
}

__device__ inline float block_reduce_max(float v, float* sm) {
    v = wave_reduce_max(v);
    int wave = threadIdx.x >> 6, lane = threadIdx.x & 63;
    if (lane == 0) sm[wave] = v;
    __syncthreads();
    float r = fmaxf(fmaxf(sm[0], sm[1]), fmaxf(sm[2], sm[3]));
    __syncthreads();
    return r;
}
__device__ inline float block_reduce_sum(float v, float* sm) {
    v = wave_reduce_sum(v);
    int wave = threadIdx.x >> 6, lane = threadIdx.x & 63;
    if (lane == 0) sm[wave] = v;
    __syncthreads();
    float r = sm[0] + sm[1] + sm[2] + sm[3];
    __syncthreads();
    return r;
}

// Kernel 1: per class row t: A = softmax(row), S[t,j] = 0.1*(1-A)/(sumA - A[t,t]),
// S[t,t] = 0.9; Srow[t] = sum_j S[t,j].
__global__ __launch_bounds__(256) void smooth_kernel(
        const float* __restrict__ ca, float* __restrict__ S,
        float* __restrict__ Srow) {
    __shared__ float sm[4];
    __shared__ float diag_sh;
    int t = blockIdx.x;
    int tid = threadIdx.x;
    const float* row = ca + (size_t)t * C;

    float v[4];
    float m = -INFINITY;
    #pragma unroll
    for (int k = 0; k < 4; k++) {
        int j = tid + k * 256;
        v[k] = (j < C) ? row[j] : -INFINITY;
        m = fmaxf(m, v[k]);
    }
    m = block_reduce_max(m, sm);

    float a[4];
    float zl = 0.f;
    #pragma unroll
    for (int k = 0; k < 4; k++) {
        int j = tid + k * 256;
        a[k] = (j < C) ? __expf(v[k] - m) : 0.f;
        zl += a[k];
    }
    float z = block_reduce_sum(zl, sm);
    float inv_z = 1.0f / z;

    float sumA_l = 0.f;
    #pragma unroll
    for (int k = 0; k < 4; k++) {
        a[k] *= inv_z;
        sumA_l += a[k];
        int j = tid + k * 256;
        if (j == t) diag_sh = a[k];   // visible after syncthreads inside next reduce
    }
    float sumA = block_reduce_sum(sumA_l, sm);

    float sums = sumA - diag_sh;
    float coef = SMOOTH / sums;
    float* Srt = S + (size_t)t * C;
    float srow_l = 0.f;
    #pragma unroll
    for (int k = 0; k < 4; k++) {
        int j = tid + k * 256;
        if (j < C) {
            float s = (j == t) ? (1.0f - SMOOTH) : (1.0f - a[k]) * coef;
            Srt[j] = s;
            srow_l += s;
        }
    }
    float srow = block_reduce_sum(srow_l, sm);
    if (tid == 0) Srow[t] = srow;
}

// Kernel 2: one wave per sample, exactly one sample per wave.
// loss_b = (m + log Z) * Srow[t]  -  dot(S[t,:], x[b,:])
// Per-block partial written to d_ws (no atomics -> deterministic).
__global__ __launch_bounds__(256) void loss_kernel(
        const float* __restrict__ x, const float* __restrict__ S,
        const float* __restrict__ Srow, const int* __restrict__ tgt,
        float* __restrict__ partials) {
    int wave = threadIdx.x >> 6, lane = threadIdx.x & 63;
    int b = blockIdx.x * 4 + wave;          // B == 4*gridDim.x exactly

    int t = tgt[b];
    float ss = Srow[t];                      // issue early, used at the end
    const f4* xr = (const f4*)(x + (size_t)b * C);
    const f4* sr = (const f4*)(S + (size_t)t * C);

    // 250 f4 per row: lane handles idx = lane + 64k, k=0..3 (k=3 partial)
    f4 xv[4], sv[4];
    #pragma unroll
    for (int k = 0; k < 3; k++) {
        sv[k] = sr[lane + k * 64];                               // S: L2-resident
        xv[k] = __builtin_nontemporal_load(xr + lane + k * 64);  // x streams once
    }
    bool last = (lane + 192) < 250;
    if (last) {
        sv[3] = sr[lane + 192];
        xv[3] = __builtin_nontemporal_load(xr + lane + 192);
    } else {
        sv[3] = f4{0.f, 0.f, 0.f, 0.f};
        xv[3] = f4{-INFINITY, -INFINITY, -INFINITY, -INFINITY};
    }

    float m = -INFINITY;
    #pragma unroll
    for (int k = 0; k < 4; k++)
        m = fmaxf(m, fmaxf(fmaxf(xv[k].x, xv[k].y), fmaxf(xv[k].z, xv[k].w)));
    m = wave_reduce_max(m);

    float zl = 0.f, dl = 0.f;
    #pragma unroll
    for (int k = 0; k < 4; k++) {
        // exp(-inf - m) = 0 on padded lanes -> safe to include
        zl += __expf(xv[k].x - m) + __expf(xv[k].y - m) +
              __expf(xv[k].z - m) + __expf(xv[k].w - m);
    }
    #pragma unroll
    for (int k = 0; k < 3; k++) {
        dl = fmaf(sv[k].x, xv[k].x, dl);
        dl = fmaf(sv[k].y, xv[k].y, dl);
        dl = fmaf(sv[k].z, xv[k].z, dl);
        dl = fmaf(sv[k].w, xv[k].w, dl);
    }
    if (last) {   // avoid 0 * -inf = NaN on padded lanes
        dl = fmaf(sv[3].x, xv[3].x, dl);
        dl = fmaf(sv[3].y, xv[3].y, dl);
        dl = fmaf(sv[3].z, xv[3].z, dl);
        dl = fmaf(sv[3].w, xv[3].w, dl);
    }
    float z = wave_reduce_sum(zl);
    float d = wave_reduce_sum(dl);
    float lb = (m + __logf(z)) * ss - d;

    __shared__ float wacc[4];
    if (lane == 0) wacc[wave] = lb;
    __syncthreads();
    if (threadIdx.x == 0)
        partials[blockIdx.x] = wacc[0] + wacc[1] + wacc[2] + wacc[3];
}

// Kernel 3: sum NBLK partials -> out = sum / B. Single block, deterministic.
__global__ __launch_bounds__(256) void reduce_kernel(
        const float* __restrict__ partials, float* __restrict__ out) {
    __shared__ float sm[4];
    const f4* p4 = (const f4*)partials;      // NBLK/4 = 4096 f4 = 256 threads * 16
    float s = 0.f;
    #pragma unroll
    for (int k = 0; k < 16; k++) {
        f4 v = p4[threadIdx.x + k * 256];
        s += (v.x + v.y) + (v.z + v.w);
    }
    s = block_reduce_sum(s, sm);
    if (threadIdx.x == 0) out[0] = s * (1.0f / (float)B);
}

extern "C" void kernel_launch(void* const* d_in, const int* in_sizes, int n_in,
                              void* d_out, int out_size, void* d_ws, size_t ws_size,
                              hipStream_t stream) {
    const float* x   = (const float*)d_in[0];
    const float* ca  = (const float*)d_in[1];
    const int*   tgt = (const int*)d_in[2];
    float* out = (float*)d_out;

    float* S        = (float*)d_ws;                  // C*C floats = 4 MB
    float* Srow     = S + (size_t)C * C;             // C floats
    float* partials = Srow + C;                      // NBLK floats = 64 KB

    smooth_kernel<<<C, 256, 0, stream>>>(ca, S, Srow);
    loss_kernel<<<NBLK, 256, 0, stream>>>(x, S, Srow, tgt, partials);
    reduce_kernel<<<1, 256, 0, stream>>>(partials, out);
}